// Round 2
// baseline (2710.993 us; speedup 1.0000x reference)
//
#include <hip/hip_runtime.h>
#include <hip/hip_bf16.h>

// HetGTAN 5-hop hetero graph attention, MI355X.
// Round 2: runtime dtype detection (fp32 vs bf16 inputs) + bf16 h storage.
//
// paper(100000,512) author(200000,256) subject(1000,128); NHID=64, NOUT=16
// ET: pa(800k) ap(800k) ps(100k) sp(100k)

#define NP 100000
#define NA 200000
#define NSJ 1000
#define EPA 800000
#define EAP 800000
#define EPS 100000
#define ESP 100000
#define ETOT 1800000
// source-slot concat: [paper(pa) | author(ap) | paper(ps) | subject(sp)]
#define NS_TOT 401000
// target-slot concat: [author(pa) | paper(ap) | subject(ps) | paper(sp)]
#define NT_TOT 401000
#define NSRC 301000
#define NCHUNK 392  // ceil(401000/1024)

typedef __attribute__((ext_vector_type(8))) short bf16x8;
typedef __attribute__((ext_vector_type(4))) float floatx4;
typedef __hip_bfloat16 bf16;

__device__ __forceinline__ float bf2f(bf16 v) { return __bfloat162float(v); }
__device__ __forceinline__ float eluf(float x) { return x > 0.f ? x : __expf(x) - 1.f; }
__device__ __forceinline__ unsigned short f2bf_bits(float f) {
    unsigned int u = __float_as_uint(f);
    return (unsigned short)((u + 0x7FFFu + ((u >> 16) & 1u)) >> 16);  // RNE
}

// dual-dtype fragment load: 8 consecutive elements starting at elem offset
__device__ __forceinline__ bf16x8 load_frag(const void* base, size_t off, int isb) {
    if (isb) return *(const bf16x8*)((const bf16*)base + off);
    const float* f = (const float*)base + off;
    bf16x8 r;
#pragma unroll
    for (int j = 0; j < 8; ++j) r[j] = (short)f2bf_bits(f[j]);
    return r;
}

// ------------- dtype detection: bf16-packed words have bf16 exponent bits in low half -------------
__global__ void detect_dtype(const unsigned int* __restrict__ xraw, int* __restrict__ flag) {
    int t = threadIdx.x;   // 64 threads
    int hits = 0;
#pragma unroll
    for (int i = 0; i < 16; ++i) {
        unsigned int w = xraw[t * 16 + i];
        unsigned int lo = w & 0xFFFFu;
        unsigned int e = (lo >> 7) & 0xFFu;   // bf16 exponent field of low half
        if (lo == 0u || (e >= 110u && e <= 140u)) hits++;
    }
#pragma unroll
    for (int o = 32; o; o >>= 1) hits += __shfl_xor(hits, o);
    if (t == 0) *flag = (hits > 512) ? 1 : 0;   // 1024 samples: bf16 ~99% hit, fp32 ~12%
}

// ------------- normalize small param arrays to fp32 -------------
__global__ void conv_param(const void* __restrict__ src, float* __restrict__ dst, int n,
                           const int* __restrict__ flagp) {
    int i = blockIdx.x * blockDim.x + threadIdx.x;
    if (i >= n) return;
    dst[i] = (*flagp) ? bf2f(((const bf16*)src)[i]) : ((const float*)src)[i];
}

// ---------------- fc1: x = relu(X @ W^T + b), W is [64,K]; writes bf16 (x == h0) ----------------
__global__ void fc1_kernel(const void* __restrict__ X, const void* __restrict__ W,
                           const float* __restrict__ B, int K, int N,
                           bf16* __restrict__ xo, const int* __restrict__ flagp)
{
    int isb = *flagp;
    int lane = threadIdx.x & 63;
    int wv = threadIdx.x >> 6;
    int grp = blockIdx.x * 4 + wv;          // 16 nodes per wave
    int ngrp = (N + 15) >> 4;
    if (grp >= ngrp) return;
    int m = lane & 15, kq = lane >> 4;
    floatx4 acc[4] = {};
    int arow = grp * 16 + m;
    if (arow >= N) arow = N - 1;            // clamp (tail group)
    for (int ks = 0; ks < K; ks += 32) {
        int k0 = ks + kq * 8;
        bf16x8 av = load_frag(X, (size_t)arow * K + k0, isb);
#pragma unroll
        for (int nb = 0; nb < 4; ++nb) {
            bf16x8 bv = load_frag(W, (size_t)(nb * 16 + m) * K + k0, isb);
            acc[nb] = __builtin_amdgcn_mfma_f32_16x16x32_bf16(av, bv, acc[nb], 0, 0, 0);
        }
    }
#pragma unroll
    for (int nb = 0; nb < 4; ++nb) {
#pragma unroll
        for (int r = 0; r < 4; ++r) {
            int row = grp * 16 + kq * 4 + r;   // C/D: row=(lane>>4)*4+reg, col=lane&15
            if (row < N) {
                int f = nb * 16 + m;
                float v = acc[nb][r] + B[f];
                xo[(size_t)row * 64 + f] = __float2bfloat16(fmaxf(v, 0.f));
            }
        }
    }
}

// ------------- precompute x1 = x·a1, w2 = exp(lrelu(x1 + x·a2)) for all 5 hops -------------
__global__ void precompute_xw(const bf16* __restrict__ xP, const bf16* __restrict__ xA,
                              const bf16* __restrict__ xS,
                              const float* __restrict__ attn1, const float* __restrict__ attn2,
                              float* __restrict__ x1buf, float* __restrict__ w2buf)
{
    int wid = (blockIdx.x * blockDim.x + threadIdx.x) >> 6;
    int lane = threadIdx.x & 63;
    if (wid >= NS_TOT) return;
    int k, n; const bf16* x;
    if (wid < NP)            { k = 0; n = wid;              x = xP; }
    else if (wid < NP + NA)  { k = 1; n = wid - NP;         x = xA; }
    else if (wid < NP+NA+NP) { k = 2; n = wid - (NP + NA);  x = xP; }
    else                     { k = 3; n = wid - (NP+NA+NP); x = xS; }
    float xv = bf2f(x[(size_t)n * 64 + lane]);
    for (int i = 0; i < 5; ++i) {
        float d1 = xv * attn1[(i * 4 + k) * 64 + lane];
        float d2 = xv * attn2[(i * 4 + k) * 64 + lane];
#pragma unroll
        for (int o = 32; o; o >>= 1) { d1 += __shfl_xor(d1, o); d2 += __shfl_xor(d2, o); }
        if (lane == 0) {
            x1buf[i * NS_TOT + wid] = d1;
            float z = d1 + d2;
            w2buf[i * NS_TOT + wid] = __expf(z > 0.f ? z : 0.2f * z);
        }
    }
}

// ---------------- CSR build (group by source over concatenated slot space) ----------------
__global__ void csr_count(const int* __restrict__ pa, const int* __restrict__ ap,
                          const int* __restrict__ ps, const int* __restrict__ sp,
                          int* __restrict__ cnt)
{
    int e = blockIdx.x * blockDim.x + threadIdx.x;
    if (e >= ETOT) return;
    int g;
    if (e < EPA)                  g = pa[e];
    else if (e < EPA + EAP)       g = NP + ap[e - EPA];
    else if (e < EPA + EAP + EPS) g = NP + NA + ps[e - (EPA + EAP)];
    else                          g = NP + NA + NP + sp[e - (EPA + EAP + EPS)];
    atomicAdd(&cnt[g], 1);
}

__global__ void scan_reduce(const int* __restrict__ cnt, int* __restrict__ partial)
{
    __shared__ int s[256];
    int base = blockIdx.x * 1024 + threadIdx.x * 4;
    int sum = 0;
#pragma unroll
    for (int r = 0; r < 4; ++r) { int i = base + r; if (i < NS_TOT) sum += cnt[i]; }
    s[threadIdx.x] = sum; __syncthreads();
    for (int o = 128; o; o >>= 1) {
        if (threadIdx.x < o) s[threadIdx.x] += s[threadIdx.x + o];
        __syncthreads();
    }
    if (!threadIdx.x) partial[blockIdx.x] = s[0];
}

__global__ void scan_partials(const int* __restrict__ partial, int* __restrict__ chunkoff)
{
    __shared__ int s[512];
    int t = threadIdx.x;
    int v = (t < NCHUNK) ? partial[t] : 0;
    s[t] = v; __syncthreads();
    for (int o = 1; o < 512; o <<= 1) {
        int add = (t >= o) ? s[t - o] : 0;
        __syncthreads();
        s[t] += add; __syncthreads();
    }
    if (t < NCHUNK) chunkoff[t] = s[t] - v;   // exclusive
}

__global__ void scan_write(const int* __restrict__ cnt, const int* __restrict__ chunkoff,
                           int* __restrict__ off, int* __restrict__ cur)
{
    __shared__ int s[256];
    int t = threadIdx.x;
    int base = blockIdx.x * 1024 + t * 4;
    int v[4]; int tsum = 0;
#pragma unroll
    for (int r = 0; r < 4; ++r) { int i = base + r; v[r] = (i < NS_TOT) ? cnt[i] : 0; tsum += v[r]; }
    s[t] = tsum; __syncthreads();
    for (int o = 1; o < 256; o <<= 1) {
        int add = (t >= o) ? s[t - o] : 0;
        __syncthreads();
        s[t] += add; __syncthreads();
    }
    int excl = s[t] - tsum + chunkoff[blockIdx.x];
#pragma unroll
    for (int r = 0; r < 4; ++r) {
        int i = base + r;
        if (i < NS_TOT) { off[i] = excl; cur[i] = excl; excl += v[r]; }
    }
}

__global__ void csr_fill(const int* __restrict__ pa, const int* __restrict__ ap,
                         const int* __restrict__ ps, const int* __restrict__ sp,
                         int* __restrict__ cur, int* __restrict__ col)
{
    int e = blockIdx.x * blockDim.x + threadIdx.x;
    if (e >= ETOT) return;
    int g, t;
    if (e < EPA)                  { g = pa[e];                        t = pa[EPA + e]; }
    else if (e < EPA + EAP)       { int le = e - EPA;                 g = NP + ap[le];           t = ap[EAP + le]; }
    else if (e < EPA + EAP + EPS) { int le = e - (EPA + EAP);         g = NP + NA + ps[le];      t = ps[EPS + le]; }
    else                          { int le = e - (EPA + EAP + EPS);   g = NP + NA + NP + sp[le]; t = sp[ESP + le]; }
    int pos = atomicAdd(&cur[g], 1);
    col[pos] = t;
}

// ---------------- per hop: h1[t] = h_old[t] · a2[hop,k] over target slots ----------------
__global__ void hop_h1(const bf16* __restrict__ hP, const bf16* __restrict__ hA,
                       const bf16* __restrict__ hS,
                       const float* __restrict__ attn2, int hop, float* __restrict__ h1)
{
    int wid = (blockIdx.x * blockDim.x + threadIdx.x) >> 6;
    int lane = threadIdx.x & 63;
    if (wid >= NT_TOT) return;
    int k, n; const bf16* h;
    if (wid < NA)                 { k = 0; n = wid;               h = hA; }
    else if (wid < NA + NP)       { k = 1; n = wid - NA;          h = hP; }
    else if (wid < NA + NP + NSJ) { k = 2; n = wid - (NA + NP);   h = hS; }
    else                          { k = 3; n = wid - (NA+NP+NSJ); h = hP; }
    float v = bf2f(h[(size_t)n * 64 + lane]) * attn2[(hop * 4 + k) * 64 + lane];
#pragma unroll
    for (int o = 32; o; o >>= 1) v += __shfl_xor(v, o);
    if (!lane) h1[wid] = v;
}

// ---------------- per hop: wave-per-source-node aggregation ----------------
__device__ __forceinline__ float agg_et(int g, int hop, float xv, int lane,
    const float* __restrict__ x1buf, const float* __restrict__ w2buf,
    const float* __restrict__ h1, int h1base, const bf16* __restrict__ ht,
    const int* __restrict__ off, const int* __restrict__ deg, const int* __restrict__ col)
{
    float x1v = x1buf[hop * NS_TOT + g];
    float w2v = w2buf[hop * NS_TOT + g];
    float acc = w2v * xv;
    float dv = w2v;
    int e0 = off[g];
    int e1 = e0 + deg[g];
    for (int e = e0; e < e1; ++e) {
        int t = col[e];
        float z = x1v + h1[h1base + t];
        float w1 = __expf(z > 0.f ? z : 0.2f * z);
        acc = fmaf(w1, bf2f(ht[(size_t)t * 64 + lane]), acc);
        dv += w1;
    }
    return acc / dv;
}

__global__ void hop_agg(const bf16* __restrict__ hPo, const bf16* __restrict__ hAo,
                        const bf16* __restrict__ hSo,
                        const bf16* __restrict__ xP, const bf16* __restrict__ xA,
                        const bf16* __restrict__ xS,
                        const float* __restrict__ x1buf, const float* __restrict__ w2buf,
                        const float* __restrict__ h1,
                        const int* __restrict__ off, const int* __restrict__ deg,
                        const int* __restrict__ col,
                        const float* __restrict__ lw, int hop,
                        bf16* __restrict__ hPn, bf16* __restrict__ hAn, bf16* __restrict__ hSn)
{
    int wid = (blockIdx.x * blockDim.x + threadIdx.x) >> 6;
    int lane = threadIdx.x & 63;
    if (wid >= NSRC) return;
    if (wid < NP) {
        int n = wid;
        float xv = bf2f(xP[(size_t)n * 64 + lane]);
        float r0 = agg_et(n,           hop, xv, lane, x1buf, w2buf, h1, 0,       hAo, off, deg, col);
        float r2 = agg_et(NP + NA + n, hop, xv, lane, x1buf, w2buf, h1, NA + NP, hSo, off, deg, col);
        float l0 = lw[hop * 4 + 0], l2 = lw[hop * 4 + 2];
        float mx = fmaxf(l0, l2);
        float e0 = __expf(l0 - mx), e2 = __expf(l2 - mx);
        float r = (e0 * r0 + e2 * r2) / (e0 + e2);
        hPn[(size_t)n * 64 + lane] = __float2bfloat16(eluf(r));
    } else if (wid < NP + NA) {
        int n = wid - NP;   // k=1 (ap): softmax over single weight == 1
        float xv = bf2f(xA[(size_t)n * 64 + lane]);
        float r = agg_et(NP + n, hop, xv, lane, x1buf, w2buf, h1, NA, hPo, off, deg, col);
        hAn[(size_t)n * 64 + lane] = __float2bfloat16(eluf(r));
    } else {
        int n = wid - (NP + NA);  // k=3 (sp)
        float xv = bf2f(xS[(size_t)n * 64 + lane]);
        float r = agg_et(NP + NA + NP + n, hop, xv, lane, x1buf, w2buf, h1, NA + NP + NSJ, hPo, off, deg, col);
        hSn[(size_t)n * 64 + lane] = __float2bfloat16(eluf(r));
    }
}

// ---------------- fc2: out = hP @ W2^T + b2 (dual-dtype store) ----------------
__global__ void fc2_kernel(const bf16* __restrict__ hP, const float* __restrict__ W2,
                           const float* __restrict__ B2, void* __restrict__ out,
                           const int* __restrict__ flagp)
{
    int isb = *flagp;
    int idx = blockIdx.x * blockDim.x + threadIdx.x;
    if (idx >= NP * 16) return;
    int n = idx >> 4, o = idx & 15;
    float acc = B2[o];
    const bf16* hr = hP + (size_t)n * 64;
#pragma unroll
    for (int j = 0; j < 64; ++j) acc = fmaf(bf2f(hr[j]), W2[o * 64 + j], acc);
    if (isb) ((bf16*)out)[idx] = __float2bfloat16(acc);
    else     ((float*)out)[idx] = acc;
}

extern "C" void kernel_launch(void* const* d_in, const int* in_sizes, int n_in,
                              void* d_out, int out_size, void* d_ws, size_t ws_size,
                              hipStream_t stream)
{
    (void)in_sizes; (void)n_in; (void)out_size; (void)ws_size;
    const void* xPi  = d_in[0];
    const void* xAi  = d_in[1];
    const void* xSi  = d_in[2];
    const void* f1pw = d_in[3];
    const void* f1pb = d_in[4];
    const void* f1aw = d_in[5];
    const void* f1ab = d_in[6];
    const void* f1sw = d_in[7];
    const void* f1sb = d_in[8];
    const void* attn1 = d_in[9];
    const void* attn2 = d_in[10];
    const void* lwp  = d_in[11];
    const void* f2w  = d_in[12];
    const void* f2b  = d_in[13];
    const int* eipa = (const int*)d_in[14];
    const int* eiap = (const int*)d_in[15];
    const int* eips = (const int*)d_in[16];
    const int* eisp = (const int*)d_in[17];

    char* p = (char*)d_ws;
    auto alloc = [&](size_t bytes) { char* r = p; p += (bytes + 255) & ~(size_t)255; return r; };
    int*  flag = (int*)alloc(4);
    bf16* xP = (bf16*)alloc((size_t)NP * 64 * 2);
    bf16* xA = (bf16*)alloc((size_t)NA * 64 * 2);
    bf16* xS = (bf16*)alloc((size_t)NSJ * 64 * 2);
    bf16* hb[2][3];
    for (int q = 0; q < 2; ++q) {
        hb[q][0] = (bf16*)alloc((size_t)NP * 64 * 2);
        hb[q][1] = (bf16*)alloc((size_t)NA * 64 * 2);
        hb[q][2] = (bf16*)alloc((size_t)NSJ * 64 * 2);
    }
    float* x1buf = (float*)alloc((size_t)5 * NS_TOT * 4);
    float* w2buf = (float*)alloc((size_t)5 * NS_TOT * 4);
    float* h1v  = (float*)alloc((size_t)NT_TOT * 4);
    int* cnt   = (int*)alloc((size_t)NS_TOT * 4);
    int* off   = (int*)alloc((size_t)NS_TOT * 4);
    int* cur   = (int*)alloc((size_t)NS_TOT * 4);
    int* colv  = (int*)alloc((size_t)ETOT * 4);
    int* partial  = (int*)alloc(512 * 4);
    int* chunkoff = (int*)alloc(512 * 4);
    float* a1c = (float*)alloc(1280 * 4);
    float* a2c = (float*)alloc(1280 * 4);
    float* lwc = (float*)alloc(20 * 4);
    float* w2c = (float*)alloc(1024 * 4);
    float* b2c = (float*)alloc(16 * 4);
    float* b1p = (float*)alloc(64 * 4);
    float* b1a = (float*)alloc(64 * 4);
    float* b1s = (float*)alloc(64 * 4);

    // dtype flag + param normalization
    detect_dtype<<<1, 64, 0, stream>>>((const unsigned int*)xPi, flag);
    conv_param<<<20, 64, 0, stream>>>(attn1, a1c, 1280, flag);
    conv_param<<<20, 64, 0, stream>>>(attn2, a2c, 1280, flag);
    conv_param<<<1, 64, 0, stream>>>(lwp, lwc, 20, flag);
    conv_param<<<16, 64, 0, stream>>>(f2w, w2c, 1024, flag);
    conv_param<<<1, 64, 0, stream>>>(f2b, b2c, 16, flag);
    conv_param<<<1, 64, 0, stream>>>(f1pb, b1p, 64, flag);
    conv_param<<<1, 64, 0, stream>>>(f1ab, b1a, 64, flag);
    conv_param<<<1, 64, 0, stream>>>(f1sb, b1s, 64, flag);

    // fc1 projections (x == h0, bf16)
    fc1_kernel<<<(6250 + 3) / 4, 256, 0, stream>>>(xPi, f1pw, b1p, 512, NP, xP, flag);
    fc1_kernel<<<(12500 + 3) / 4, 256, 0, stream>>>(xAi, f1aw, b1a, 256, NA, xA, flag);
    fc1_kernel<<<(63 + 3) / 4, 256, 0, stream>>>(xSi, f1sw, b1s, 128, NSJ, xS, flag);

    // per-source attention scalars for all hops
    precompute_xw<<<NS_TOT / 4, 256, 0, stream>>>(xP, xA, xS, a1c, a2c, x1buf, w2buf);

    // CSR build
    hipMemsetAsync(cnt, 0, (size_t)NS_TOT * 4, stream);
    hipMemsetAsync(colv, 0, (size_t)ETOT * 4, stream);   // insurance: holes -> valid index 0
    csr_count<<<(ETOT + 255) / 256, 256, 0, stream>>>(eipa, eiap, eips, eisp, cnt);
    scan_reduce<<<NCHUNK, 256, 0, stream>>>(cnt, partial);
    scan_partials<<<1, 512, 0, stream>>>(partial, chunkoff);
    scan_write<<<NCHUNK, 256, 0, stream>>>(cnt, chunkoff, off, cur);
    csr_fill<<<(ETOT + 255) / 256, 256, 0, stream>>>(eipa, eiap, eips, eisp, cur, colv);

    // hops: h(0) = x buffers; then alternate hb[0]/hb[1]
    const bf16* cP = xP; const bf16* cA = xA; const bf16* cS = xS;
    for (int i = 0; i < 5; ++i) {
        bf16* nP = hb[i & 1][0]; bf16* nA = hb[i & 1][1]; bf16* nS = hb[i & 1][2];
        hop_h1<<<NT_TOT / 4, 256, 0, stream>>>(cP, cA, cS, a2c, i, h1v);
        hop_agg<<<NSRC / 4 + 1, 256, 0, stream>>>(cP, cA, cS, xP, xA, xS,
                                                  x1buf, w2buf, h1v, off, cnt, colv,
                                                  lwc, i, nP, nA, nS);
        cP = nP; cA = nA; cS = nS;
    }

    fc2_kernel<<<(NP * 16 + 255) / 256, 256, 0, stream>>>(cP, w2c, b2c, d_out, flag);
}

// Round 3
// 1935.881 us; speedup vs baseline: 1.4004x; 1.4004x over previous
//
#include <hip/hip_runtime.h>
#include <hip/hip_bf16.h>

// HetGTAN 5-hop hetero graph attention, MI355X.
// Round 3: quarter-wave aggregation (4 edges in flight, lane=4 features),
// vectorized fp32 fc1 path, merged param conversion.

#define NP 100000
#define NA 200000
#define NSJ 1000
#define EPA 800000
#define EAP 800000
#define EPS 100000
#define ESP 100000
#define ETOT 1800000
// source-slot concat: [paper(pa) | author(ap) | paper(ps) | subject(sp)]
#define NS_TOT 401000
// target-slot concat: [author(pa) | paper(ap) | subject(ps) | paper(sp)]
#define NT_TOT 401000
#define NSRC 301000
#define NCHUNK 392  // ceil(401000/1024)

typedef __attribute__((ext_vector_type(8))) short bf16x8;
typedef __attribute__((ext_vector_type(4))) float floatx4;
typedef __hip_bfloat16 bf16;

__device__ __forceinline__ float bf2f(bf16 v) { return __bfloat162float(v); }
__device__ __forceinline__ float us2f(unsigned short u) { return __uint_as_float((unsigned)u << 16); }
__device__ __forceinline__ float eluf(float x) { return x > 0.f ? x : __expf(x) - 1.f; }
__device__ __forceinline__ unsigned short f2bf_bits(float f) {
    unsigned int u = __float_as_uint(f);
    return (unsigned short)((u + 0x7FFFu + ((u >> 16) & 1u)) >> 16);  // RNE
}

// dual-dtype MFMA fragment load: 8 consecutive elements at elem offset
__device__ __forceinline__ bf16x8 load_frag(const void* base, size_t off, int isb) {
    if (isb) return *(const bf16x8*)((const bf16*)base + off);
    const float4* f = (const float4*)((const float*)base + off);  // off%8==0 -> 16B aligned
    float4 a = f[0], b = f[1];
    bf16x8 r;
    r[0] = (short)f2bf_bits(a.x); r[1] = (short)f2bf_bits(a.y);
    r[2] = (short)f2bf_bits(a.z); r[3] = (short)f2bf_bits(a.w);
    r[4] = (short)f2bf_bits(b.x); r[5] = (short)f2bf_bits(b.y);
    r[6] = (short)f2bf_bits(b.z); r[7] = (short)f2bf_bits(b.w);
    return r;
}

// ---------------- dtype detection ----------------
__global__ void detect_dtype(const unsigned int* __restrict__ xraw, int* __restrict__ flag) {
    int t = threadIdx.x;   // 64 threads
    int hits = 0;
#pragma unroll
    for (int i = 0; i < 16; ++i) {
        unsigned int w = xraw[t * 16 + i];
        unsigned int lo = w & 0xFFFFu;
        unsigned int e = (lo >> 7) & 0xFFu;   // bf16 exponent field of low half
        if (lo == 0u || (e >= 110u && e <= 140u)) hits++;
    }
#pragma unroll
    for (int o = 32; o; o >>= 1) hits += __shfl_xor(hits, o);
    if (t == 0) *flag = (hits > 512) ? 1 : 0;   // bf16 ~99% hit, fp32 ~12%
}

// ---------------- merged param normalization to fp32 ----------------
__global__ void conv_all(const void* a1, const void* a2, const void* lw, const void* w2,
                         const void* b2, const void* bp, const void* ba, const void* bs,
                         float* a1c, float* a2c, float* lwc, float* w2c, float* b2c,
                         float* b1p, float* b1a, float* b1s, const int* __restrict__ flagp)
{
    int i = blockIdx.x * blockDim.x + threadIdx.x;
    int isb = *flagp;
    auto cv = [&](const void* s, int j) -> float {
        return isb ? bf2f(((const bf16*)s)[j]) : ((const float*)s)[j];
    };
    if (i < 1280)      a1c[i] = cv(a1, i);
    else if (i < 2560) a2c[i - 1280] = cv(a2, i - 1280);
    else if (i < 2580) lwc[i - 2560] = cv(lw, i - 2560);
    else if (i < 3604) w2c[i - 2580] = cv(w2, i - 2580);
    else if (i < 3620) b2c[i - 3604] = cv(b2, i - 3604);
    else if (i < 3684) b1p[i - 3620] = cv(bp, i - 3620);
    else if (i < 3748) b1a[i - 3684] = cv(ba, i - 3684);
    else if (i < 3812) b1s[i - 3748] = cv(bs, i - 3748);
}

// ---------------- fc1: x = relu(X @ W^T + b), W is [64,K]; writes bf16 ----------------
__global__ void fc1_kernel(const void* __restrict__ X, const void* __restrict__ W,
                           const float* __restrict__ B, int K, int N,
                           bf16* __restrict__ xo, const int* __restrict__ flagp)
{
    int isb = *flagp;
    int lane = threadIdx.x & 63;
    int wv = threadIdx.x >> 6;
    int grp = blockIdx.x * 4 + wv;          // 16 nodes per wave
    int ngrp = (N + 15) >> 4;
    if (grp >= ngrp) return;
    int m = lane & 15, kq = lane >> 4;
    floatx4 acc[4] = {};
    int arow = grp * 16 + m;
    if (arow >= N) arow = N - 1;            // clamp (tail group)
    for (int ks = 0; ks < K; ks += 32) {
        int k0 = ks + kq * 8;
        bf16x8 av = load_frag(X, (size_t)arow * K + k0, isb);
#pragma unroll
        for (int nb = 0; nb < 4; ++nb) {
            bf16x8 bv = load_frag(W, (size_t)(nb * 16 + m) * K + k0, isb);
            acc[nb] = __builtin_amdgcn_mfma_f32_16x16x32_bf16(av, bv, acc[nb], 0, 0, 0);
        }
    }
#pragma unroll
    for (int nb = 0; nb < 4; ++nb) {
#pragma unroll
        for (int r = 0; r < 4; ++r) {
            int row = grp * 16 + kq * 4 + r;   // C/D: row=(lane>>4)*4+reg, col=lane&15
            if (row < N) {
                int f = nb * 16 + m;
                float v = acc[nb][r] + B[f];
                xo[(size_t)row * 64 + f] = __float2bfloat16(fmaxf(v, 0.f));
            }
        }
    }
}

// ------------- precompute x1 = x·a1, w2 = exp(lrelu(x1 + x·a2)) for all 5 hops -------------
__global__ void precompute_xw(const bf16* __restrict__ xP, const bf16* __restrict__ xA,
                              const bf16* __restrict__ xS,
                              const float* __restrict__ attn1, const float* __restrict__ attn2,
                              float* __restrict__ x1buf, float* __restrict__ w2buf)
{
    int wid = (blockIdx.x * blockDim.x + threadIdx.x) >> 6;
    int lane = threadIdx.x & 63;
    if (wid >= NS_TOT) return;
    int k, n; const bf16* x;
    if (wid < NP)            { k = 0; n = wid;              x = xP; }
    else if (wid < NP + NA)  { k = 1; n = wid - NP;         x = xA; }
    else if (wid < NP+NA+NP) { k = 2; n = wid - (NP + NA);  x = xP; }
    else                     { k = 3; n = wid - (NP+NA+NP); x = xS; }
    float xv = bf2f(x[(size_t)n * 64 + lane]);
    for (int i = 0; i < 5; ++i) {
        float d1 = xv * attn1[(i * 4 + k) * 64 + lane];
        float d2 = xv * attn2[(i * 4 + k) * 64 + lane];
#pragma unroll
        for (int o = 32; o; o >>= 1) { d1 += __shfl_xor(d1, o); d2 += __shfl_xor(d2, o); }
        if (lane == 0) {
            x1buf[i * NS_TOT + wid] = d1;
            float z = d1 + d2;
            w2buf[i * NS_TOT + wid] = __expf(z > 0.f ? z : 0.2f * z);
        }
    }
}

// ---------------- CSR build ----------------
__global__ void csr_count(const int* __restrict__ pa, const int* __restrict__ ap,
                          const int* __restrict__ ps, const int* __restrict__ sp,
                          int* __restrict__ cnt)
{
    int e = blockIdx.x * blockDim.x + threadIdx.x;
    if (e >= ETOT) return;
    int g;
    if (e < EPA)                  g = pa[e];
    else if (e < EPA + EAP)       g = NP + ap[e - EPA];
    else if (e < EPA + EAP + EPS) g = NP + NA + ps[e - (EPA + EAP)];
    else                          g = NP + NA + NP + sp[e - (EPA + EAP + EPS)];
    atomicAdd(&cnt[g], 1);
}

__global__ void scan_reduce(const int* __restrict__ cnt, int* __restrict__ partial)
{
    __shared__ int s[256];
    int base = blockIdx.x * 1024 + threadIdx.x * 4;
    int sum = 0;
#pragma unroll
    for (int r = 0; r < 4; ++r) { int i = base + r; if (i < NS_TOT) sum += cnt[i]; }
    s[threadIdx.x] = sum; __syncthreads();
    for (int o = 128; o; o >>= 1) {
        if (threadIdx.x < o) s[threadIdx.x] += s[threadIdx.x + o];
        __syncthreads();
    }
    if (!threadIdx.x) partial[blockIdx.x] = s[0];
}

__global__ void scan_partials(const int* __restrict__ partial, int* __restrict__ chunkoff)
{
    __shared__ int s[512];
    int t = threadIdx.x;
    int v = (t < NCHUNK) ? partial[t] : 0;
    s[t] = v; __syncthreads();
    for (int o = 1; o < 512; o <<= 1) {
        int add = (t >= o) ? s[t - o] : 0;
        __syncthreads();
        s[t] += add; __syncthreads();
    }
    if (t < NCHUNK) chunkoff[t] = s[t] - v;   // exclusive
}

__global__ void scan_write(const int* __restrict__ cnt, const int* __restrict__ chunkoff,
                           int* __restrict__ off, int* __restrict__ cur)
{
    __shared__ int s[256];
    int t = threadIdx.x;
    int base = blockIdx.x * 1024 + t * 4;
    int v[4]; int tsum = 0;
#pragma unroll
    for (int r = 0; r < 4; ++r) { int i = base + r; v[r] = (i < NS_TOT) ? cnt[i] : 0; tsum += v[r]; }
    s[t] = tsum; __syncthreads();
    for (int o = 1; o < 256; o <<= 1) {
        int add = (t >= o) ? s[t - o] : 0;
        __syncthreads();
        s[t] += add; __syncthreads();
    }
    int excl = s[t] - tsum + chunkoff[blockIdx.x];
#pragma unroll
    for (int r = 0; r < 4; ++r) {
        int i = base + r;
        if (i < NS_TOT) { off[i] = excl; cur[i] = excl; excl += v[r]; }
    }
}

__global__ void csr_fill(const int* __restrict__ pa, const int* __restrict__ ap,
                         const int* __restrict__ ps, const int* __restrict__ sp,
                         int* __restrict__ cur, int* __restrict__ col)
{
    int e = blockIdx.x * blockDim.x + threadIdx.x;
    if (e >= ETOT) return;
    int g, t;
    if (e < EPA)                  { g = pa[e];                        t = pa[EPA + e]; }
    else if (e < EPA + EAP)       { int le = e - EPA;                 g = NP + ap[le];           t = ap[EAP + le]; }
    else if (e < EPA + EAP + EPS) { int le = e - (EPA + EAP);         g = NP + NA + ps[le];      t = ps[EPS + le]; }
    else                          { int le = e - (EPA + EAP + EPS);   g = NP + NA + NP + sp[le]; t = sp[ESP + le]; }
    int pos = atomicAdd(&cur[g], 1);
    col[pos] = t;
}

// ------- per hop: h1[t] = h_old[t] · a2[hop,k]; quarter-wave (4 slots/wave) -------
__global__ void hop_h1(const bf16* __restrict__ hP, const bf16* __restrict__ hA,
                       const bf16* __restrict__ hS,
                       const float* __restrict__ attn2, int hop, float* __restrict__ h1)
{
    int wave = (blockIdx.x * blockDim.x + threadIdx.x) >> 6;
    int lane = threadIdx.x & 63;
    int q = lane >> 4, fl = lane & 15;
    int wid = wave * 4 + q;
    if (wid >= NT_TOT) return;
    int k, n; const bf16* h;
    if (wid < NA)                 { k = 0; n = wid;               h = hA; }
    else if (wid < NA + NP)       { k = 1; n = wid - NA;          h = hP; }
    else if (wid < NA + NP + NSJ) { k = 2; n = wid - (NA + NP);   h = hS; }
    else                          { k = 3; n = wid - (NA+NP+NSJ); h = hP; }
    ushort4 hv = *(const ushort4*)((const unsigned short*)h + (size_t)n * 64 + fl * 4);
    const float4 a2 = *(const float4*)(attn2 + (hop * 4 + k) * 64 + fl * 4);
    float v = us2f(hv.x) * a2.x + us2f(hv.y) * a2.y + us2f(hv.z) * a2.z + us2f(hv.w) * a2.w;
#pragma unroll
    for (int o = 1; o <= 8; o <<= 1) v += __shfl_xor(v, o);   // sum within quarter
    if (fl == 0) h1[wid] = v;
}

// ------- per hop: quarter-wave aggregation (4 edges in flight, lane = 4 feats) -------
__device__ __forceinline__ float4 agg_et4(int g, int hop, int q, int fl, float4 xv,
    const float* __restrict__ x1buf, const float* __restrict__ w2buf,
    const float* __restrict__ h1, int h1base, const bf16* __restrict__ ht,
    const int* __restrict__ off, const int* __restrict__ deg, const int* __restrict__ col)
{
    float x1v = x1buf[hop * NS_TOT + g];
    float4 acc = {0.f, 0.f, 0.f, 0.f};
    float dv = 0.f;
    int e0 = off[g];
    int e1 = e0 + deg[g];
    for (int e = e0 + q; e < e1; e += 4) {
        int t = col[e];
        float z = x1v + h1[h1base + t];
        float w1 = __expf(z > 0.f ? z : 0.2f * z);
        ushort4 hv = *(const ushort4*)((const unsigned short*)ht + (size_t)t * 64 + fl * 4);
        acc.x = fmaf(w1, us2f(hv.x), acc.x);
        acc.y = fmaf(w1, us2f(hv.y), acc.y);
        acc.z = fmaf(w1, us2f(hv.z), acc.z);
        acc.w = fmaf(w1, us2f(hv.w), acc.w);
        dv += w1;
    }
#pragma unroll
    for (int o = 16; o <= 32; o <<= 1) {   // combine quarters
        acc.x += __shfl_xor(acc.x, o);
        acc.y += __shfl_xor(acc.y, o);
        acc.z += __shfl_xor(acc.z, o);
        acc.w += __shfl_xor(acc.w, o);
        dv += __shfl_xor(dv, o);
    }
    float w2v = w2buf[hop * NS_TOT + g];
    dv += w2v;
    float inv = 1.f / dv;
    float4 r;
    r.x = (acc.x + w2v * xv.x) * inv;
    r.y = (acc.y + w2v * xv.y) * inv;
    r.z = (acc.z + w2v * xv.z) * inv;
    r.w = (acc.w + w2v * xv.w) * inv;
    return r;
}

__global__ void hop_agg(const bf16* __restrict__ hPo, const bf16* __restrict__ hAo,
                        const bf16* __restrict__ hSo,
                        const bf16* __restrict__ xP, const bf16* __restrict__ xA,
                        const bf16* __restrict__ xS,
                        const float* __restrict__ x1buf, const float* __restrict__ w2buf,
                        const float* __restrict__ h1,
                        const int* __restrict__ off, const int* __restrict__ deg,
                        const int* __restrict__ col,
                        const float* __restrict__ lw, int hop,
                        bf16* __restrict__ hPn, bf16* __restrict__ hAn, bf16* __restrict__ hSn)
{
    int wid = (blockIdx.x * blockDim.x + threadIdx.x) >> 6;   // one wave per source node
    int lane = threadIdx.x & 63;
    int q = lane >> 4, fl = lane & 15;
    if (wid >= NSRC) return;
    float4 r;
    bf16* dst;
    int n;
    if (wid < NP) {
        n = wid;
        ushort4 xu = *(const ushort4*)((const unsigned short*)xP + (size_t)n * 64 + fl * 4);
        float4 xv = {us2f(xu.x), us2f(xu.y), us2f(xu.z), us2f(xu.w)};
        float4 r0 = agg_et4(n,           hop, q, fl, xv, x1buf, w2buf, h1, 0,       hAo, off, deg, col);
        float4 r2 = agg_et4(NP + NA + n, hop, q, fl, xv, x1buf, w2buf, h1, NA + NP, hSo, off, deg, col);
        float l0 = lw[hop * 4 + 0], l2 = lw[hop * 4 + 2];
        float mx = fmaxf(l0, l2);
        float e0 = __expf(l0 - mx), e2 = __expf(l2 - mx);
        float inv = 1.f / (e0 + e2);
        r.x = (e0 * r0.x + e2 * r2.x) * inv;
        r.y = (e0 * r0.y + e2 * r2.y) * inv;
        r.z = (e0 * r0.z + e2 * r2.z) * inv;
        r.w = (e0 * r0.w + e2 * r2.w) * inv;
        dst = hPn;
    } else if (wid < NP + NA) {
        n = wid - NP;   // ap: softmax over single weight == 1
        ushort4 xu = *(const ushort4*)((const unsigned short*)xA + (size_t)n * 64 + fl * 4);
        float4 xv = {us2f(xu.x), us2f(xu.y), us2f(xu.z), us2f(xu.w)};
        r = agg_et4(NP + n, hop, q, fl, xv, x1buf, w2buf, h1, NA, hPo, off, deg, col);
        dst = hAn;
    } else {
        n = wid - (NP + NA);  // sp
        ushort4 xu = *(const ushort4*)((const unsigned short*)xS + (size_t)n * 64 + fl * 4);
        float4 xv = {us2f(xu.x), us2f(xu.y), us2f(xu.z), us2f(xu.w)};
        r = agg_et4(NP + NA + NP + n, hop, q, fl, xv, x1buf, w2buf, h1, NA + NP + NSJ, hPo, off, deg, col);
        dst = hSn;
    }
    if (q == 0) {
        ushort4 st;
        st.x = f2bf_bits(eluf(r.x));
        st.y = f2bf_bits(eluf(r.y));
        st.z = f2bf_bits(eluf(r.z));
        st.w = f2bf_bits(eluf(r.w));
        *(ushort4*)((unsigned short*)dst + (size_t)n * 64 + fl * 4) = st;
    }
}

// ---------------- fc2: out = hP @ W2^T + b2 (dual-dtype store) ----------------
__global__ void fc2_kernel(const bf16* __restrict__ hP, const float* __restrict__ W2,
                           const float* __restrict__ B2, void* __restrict__ out,
                           const int* __restrict__ flagp)
{
    int isb = *flagp;
    int idx = blockIdx.x * blockDim.x + threadIdx.x;
    if (idx >= NP * 16) return;
    int n = idx >> 4, o = idx & 15;
    float acc = B2[o];
    const bf16* hr = hP + (size_t)n * 64;
#pragma unroll
    for (int j = 0; j < 64; ++j) acc = fmaf(bf2f(hr[j]), W2[o * 64 + j], acc);
    if (isb) ((bf16*)out)[idx] = __float2bfloat16(acc);
    else     ((float*)out)[idx] = acc;
}

extern "C" void kernel_launch(void* const* d_in, const int* in_sizes, int n_in,
                              void* d_out, int out_size, void* d_ws, size_t ws_size,
                              hipStream_t stream)
{
    (void)in_sizes; (void)n_in; (void)out_size; (void)ws_size;
    const void* xPi  = d_in[0];
    const void* xAi  = d_in[1];
    const void* xSi  = d_in[2];
    const void* f1pw = d_in[3];
    const void* f1pb = d_in[4];
    const void* f1aw = d_in[5];
    const void* f1ab = d_in[6];
    const void* f1sw = d_in[7];
    const void* f1sb = d_in[8];
    const void* attn1 = d_in[9];
    const void* attn2 = d_in[10];
    const void* lwp  = d_in[11];
    const void* f2w  = d_in[12];
    const void* f2b  = d_in[13];
    const int* eipa = (const int*)d_in[14];
    const int* eiap = (const int*)d_in[15];
    const int* eips = (const int*)d_in[16];
    const int* eisp = (const int*)d_in[17];

    char* p = (char*)d_ws;
    auto alloc = [&](size_t bytes) { char* r = p; p += (bytes + 255) & ~(size_t)255; return r; };
    int*  flag = (int*)alloc(4);
    bf16* xP = (bf16*)alloc((size_t)NP * 64 * 2);
    bf16* xA = (bf16*)alloc((size_t)NA * 64 * 2);
    bf16* xS = (bf16*)alloc((size_t)NSJ * 64 * 2);
    bf16* hb[2][3];
    for (int qq = 0; qq < 2; ++qq) {
        hb[qq][0] = (bf16*)alloc((size_t)NP * 64 * 2);
        hb[qq][1] = (bf16*)alloc((size_t)NA * 64 * 2);
        hb[qq][2] = (bf16*)alloc((size_t)NSJ * 64 * 2);
    }
    float* x1buf = (float*)alloc((size_t)5 * NS_TOT * 4);
    float* w2buf = (float*)alloc((size_t)5 * NS_TOT * 4);
    float* h1v  = (float*)alloc((size_t)NT_TOT * 4);
    int* cnt   = (int*)alloc((size_t)NS_TOT * 4);
    int* off   = (int*)alloc((size_t)NS_TOT * 4);
    int* cur   = (int*)alloc((size_t)NS_TOT * 4);
    int* colv  = (int*)alloc((size_t)ETOT * 4);
    int* partial  = (int*)alloc(512 * 4);
    int* chunkoff = (int*)alloc(512 * 4);
    float* a1c = (float*)alloc(1280 * 4);
    float* a2c = (float*)alloc(1280 * 4);
    float* lwc = (float*)alloc(20 * 4);
    float* w2c = (float*)alloc(1024 * 4);
    float* b2c = (float*)alloc(16 * 4);
    float* b1p = (float*)alloc(64 * 4);
    float* b1a = (float*)alloc(64 * 4);
    float* b1s = (float*)alloc(64 * 4);

    // dtype flag + param normalization (single merged launch)
    detect_dtype<<<1, 64, 0, stream>>>((const unsigned int*)xPi, flag);
    conv_all<<<15, 256, 0, stream>>>(attn1, attn2, lwp, f2w, f2b, f1pb, f1ab, f1sb,
                                     a1c, a2c, lwc, w2c, b2c, b1p, b1a, b1s, flag);

    // fc1 projections (x == h0, bf16)
    fc1_kernel<<<(6250 + 3) / 4, 256, 0, stream>>>(xPi, f1pw, b1p, 512, NP, xP, flag);
    fc1_kernel<<<(12500 + 3) / 4, 256, 0, stream>>>(xAi, f1aw, b1a, 256, NA, xA, flag);
    fc1_kernel<<<(63 + 3) / 4, 256, 0, stream>>>(xSi, f1sw, b1s, 128, NSJ, xS, flag);

    // per-source attention scalars for all hops
    precompute_xw<<<NS_TOT / 4, 256, 0, stream>>>(xP, xA, xS, a1c, a2c, x1buf, w2buf);

    // CSR build
    hipMemsetAsync(cnt, 0, (size_t)NS_TOT * 4, stream);
    csr_count<<<(ETOT + 255) / 256, 256, 0, stream>>>(eipa, eiap, eips, eisp, cnt);
    scan_reduce<<<NCHUNK, 256, 0, stream>>>(cnt, partial);
    scan_partials<<<1, 512, 0, stream>>>(partial, chunkoff);
    scan_write<<<NCHUNK, 256, 0, stream>>>(cnt, chunkoff, off, cur);
    csr_fill<<<(ETOT + 255) / 256, 256, 0, stream>>>(eipa, eiap, eips, eisp, cur, colv);

    // hops: h(0) = x buffers; then alternate hb[0]/hb[1]
    const bf16* cP = xP; const bf16* cA = xA; const bf16* cS = xS;
    for (int i = 0; i < 5; ++i) {
        bf16* nPb = hb[i & 1][0]; bf16* nAb = hb[i & 1][1]; bf16* nSb = hb[i & 1][2];
        hop_h1<<<(NT_TOT + 15) / 16, 256, 0, stream>>>(cP, cA, cS, a2c, i, h1v);
        hop_agg<<<(NSRC + 3) / 4, 256, 0, stream>>>(cP, cA, cS, xP, xA, xS,
                                                    x1buf, w2buf, h1v, off, cnt, colv,
                                                    lwc, i, nPb, nAb, nSb);
        cP = nPb; cA = nAb; cS = nSb;
    }

    fc2_kernel<<<(NP * 16 + 255) / 256, 256, 0, stream>>>(cP, w2c, b2c, d_out, flag);
}